// Round 17
// baseline (171.180 us; speedup 1.0000x reference)
//
#include <hip/hip_runtime.h>
#include <cstdint>
#include <cmath>

#define HWSZ    15000      // H*W = 100*150
#define W_FEAT  150
#define A_NUM   9
#define NPER    135000     // A_NUM * HWSZ
#define B_NUM   16
#define PRE_NMS 6000
#define POST_NMS 300
#define NBINS   16384      // top-14-bit histogram
#define GCAP    2048       // per-group sort capacity
#define NGRP    6          // ceil(6000/1024)

// 9 base anchors from generate_anchors(16,[0.5,1,2],[8,16,32]).
__device__ __constant__ float ANC[9][4] = {
    {-84.f,  -40.f,  99.f,  55.f},
    {-176.f, -88.f, 191.f, 103.f},
    {-360.f,-184.f, 375.f, 199.f},
    {-56.f,  -56.f,  71.f,  71.f},
    {-120.f,-120.f, 135.f, 135.f},
    {-248.f,-248.f, 263.f, 263.f},
    {-36.f,  -80.f,  51.f,  95.f},
    {-80.f, -168.f,  95.f, 183.f},
    {-168.f,-344.f, 183.f, 359.f}};

__device__ __forceinline__ uint32_t fkey(float s) {
    uint32_t u = __float_as_uint(s);
    return (u & 0x80000000u) ? ~u : (u | 0x80000000u);  // monotone key
}

// EXACT replacement for  __fdiv_rn(inter,den) > 0.7f  (see r6 derivation):
// m = midpoint(0.7f,next(0.7f)) = 0x1.666667p-1 (25 bits); m*(double)den exact.
__device__ __forceinline__ bool iou_gt(const float4& q, float qa,
                                       const float4& c, float ca) {
    float xx1 = fmaxf(q.x, c.x);
    float yy1 = fmaxf(q.y, c.y);
    float xx2 = fminf(q.z, c.z);
    float yy2 = fminf(q.w, c.w);
    float iw = fmaxf(0.0f, __fadd_rn(__fsub_rn(xx2, xx1), 1.0f));
    float ih = fmaxf(0.0f, __fadd_rn(__fsub_rn(yy2, yy1), 1.0f));
    float inter = __fmul_rn(iw, ih);
    float den = __fsub_rn(__fadd_rn(qa, ca), inter);
    return (double)inter >= 0x1.666667p-1 * (double)den;
}

__device__ __forceinline__ float area_of(const float4& c) {
    return __fmul_rn(__fadd_rn(__fsub_rn(c.z, c.x), 1.0f),
                     __fadd_rn(__fsub_rn(c.w, c.y), 1.0f));
}

// ---- K1: per-slice private histograms (no global atomics) -------------------
__global__ __launch_bounds__(1024) void k_hist(const float* __restrict__ scores,
                                               uint32_t* __restrict__ subhist) {
    __shared__ uint32_t hist[NBINS];          // 64KB
    int b = blockIdx.y, sx = blockIdx.x, S = gridDim.x, tid = threadIdx.x;
    for (int i = tid; i < NBINS; i += 1024) hist[i] = 0;
    __syncthreads();
    const float4* sc4 = (const float4*)(scores + (size_t)(b * 18 + 9) * HWSZ);
    int nf4 = NPER / 4;                       // 33750
    int per = (nf4 + S - 1) / S;
    int lo = sx * per, hi = min(lo + per, nf4);
    for (int i = lo + tid; i < hi; i += 1024) {
        float4 v = sc4[i];
        atomicAdd(&hist[fkey(v.x) >> 18], 1u);
        atomicAdd(&hist[fkey(v.y) >> 18], 1u);
        atomicAdd(&hist[fkey(v.z) >> 18], 1u);
        atomicAdd(&hist[fkey(v.w) >> 18], 1u);
    }
    __syncthreads();
    uint32_t* out = subhist + ((size_t)b * S + sx) * NBINS;
    for (int i = tid; i < NBINS; i += 1024) out[i] = hist[i];
}

// ---- K2: per-bin exclusive-from-top cum table + group bases + gcnt zero -----
__global__ __launch_bounds__(1024) void k_scan(const uint32_t* __restrict__ subhist,
                                               int S, uint32_t* __restrict__ scum,
                                               uint32_t* __restrict__ gbase,
                                               uint32_t* __restrict__ gcnt) {
    __shared__ uint32_t tl[NBINS];            // 64KB summed hist
    __shared__ uint32_t psum[1024];
    __shared__ uint32_t gb[8];
    int b = blockIdx.x, tid = threadIdx.x;
    for (int i = tid; i < NBINS; i += 1024) {
        uint32_t t = 0;
        for (int u = 0; u < S; ++u) t += subhist[((size_t)b * S + u) * NBINS + i];
        tl[i] = t;
    }
    if (tid < 8) gb[tid] = 0xFFFFFFFFu;
    if (tid < NGRP) gcnt[(b * NGRP + tid) * 16] = 0;   // replaces memset dispatch
    __syncthreads();
    int base = NBINS - 16 * (tid + 1);        // chunk tid: descending bins
    uint32_t csum = 0;
#pragma unroll
    for (int i = 0; i < 16; ++i) csum += tl[base + i];
    psum[tid] = csum;
    __syncthreads();
    for (int off = 1; off < 1024; off <<= 1) {
        uint32_t v = (tid >= off) ? psum[tid - off] : 0u;
        __syncthreads();
        psum[tid] += v;
        __syncthreads();
    }
    uint32_t c = tid ? psum[tid - 1] : 0u;    // exclusive cum before this chunk
    for (int i = 15; i >= 0; --i) {           // bins descending within chunk
        uint32_t t = tl[base + i];
        scum[(size_t)b * NBINS + base + i] = c;
        if (t && c < PRE_NMS) atomicMin(&gb[c >> 10], c);
        c += t;
    }
    __syncthreads();
    if (tid < 8) gbase[b * 8 + tid] = gb[tid];
}

// ---- K3: single-pass compact -> per-group global candidate buffers ----------
__global__ __launch_bounds__(1024) void k_compact(
        const float* __restrict__ scores, const uint32_t* __restrict__ scum,
        uint64_t* __restrict__ cand, uint32_t* __restrict__ gcnt) {
    __shared__ uint32_t sl[NBINS];            // 64KB scum cache
    __shared__ uint32_t lc[NGRP], lb[NGRP];
    int b = blockIdx.y, sx = blockIdx.x, S = gridDim.x, tid = threadIdx.x;
    for (int i = tid; i < NBINS; i += 1024) sl[i] = scum[(size_t)b * NBINS + i];
    if (tid < NGRP) lc[tid] = 0;
    __syncthreads();
    const float4* sc4 = (const float4*)(scores + (size_t)(b * 18 + 9) * HWSZ);
    int nf4 = NPER / 4;
    int per = (nf4 + S - 1) / S;
    int lo = sx * per, hi = min(lo + per, nf4);
    for (int i0 = lo; i0 < hi; i0 += 1024) {
        int i = i0 + tid;
        bool w[4];
        uint32_t gg[4], pp[4];
        uint64_t rec[4];
#pragma unroll
        for (int c = 0; c < 4; ++c) w[c] = false;
        if (i < hi) {
            float4 v = sc4[i];
            float cc[4] = {v.x, v.y, v.z, v.w};
#pragma unroll
            for (int c = 0; c < 4; ++c) {
                uint32_t k = fkey(cc[c]);
                uint32_t sc = sl[k >> 18];
                if (sc < PRE_NMS) {           // in top-6000 by bin
                    w[c] = true;
                    gg[c] = sc >> 10;         // rank group 0..5
                    pp[c] = atomicAdd(&lc[gg[c]], 1u);
                    int e = 4 * i + c;        // e = a*HWSZ + p
                    int a = e / HWSZ, p = e - a * HWSZ;
                    rec[c] = ((uint64_t)(~k) << 32) | (uint32_t)(p * A_NUM + a);
                }
            }
        }
        __syncthreads();
        if (tid < NGRP && lc[tid])            // one global atomic per group/chunk
            lb[tid] = atomicAdd(&gcnt[(b * NGRP + tid) * 16], lc[tid]);
        __syncthreads();
#pragma unroll
        for (int c = 0; c < 4; ++c)
            if (w[c]) {
                uint32_t pos = lb[gg[c]] + pp[c];
                if (pos < GCAP)
                    cand[((size_t)b * NGRP + gg[c]) * GCAP + pos] = rec[c];
            }
        __syncthreads();
        if (tid < NGRP) lc[tid] = 0;
        __syncthreads();
    }
}

// ---- K4: per-group bitonic(2048) + decode (no score re-read) ----------------
__global__ __launch_bounds__(1024) void k_group(
        const uint64_t* __restrict__ cand, const uint32_t* __restrict__ gcnt,
        const float* __restrict__ deltas, const float* __restrict__ im_info,
        const uint32_t* __restrict__ gbase, float4* __restrict__ boxes) {
    __shared__ uint64_t s[GCAP];              // 16KB sort buffer
    int b = blockIdx.y, g = blockIdx.x, tid = threadIdx.x;
    uint32_t base = gbase[b * 8 + g];
    if (base == 0xFFFFFFFFu) return;          // empty group
    uint32_t cnt = min(gcnt[(b * NGRP + g) * 16], (uint32_t)GCAP);
    for (int i = tid; i < GCAP; i += 1024)
        s[i] = (i < (int)cnt) ? cand[((size_t)b * NGRP + g) * GCAP + i] : ~0ull;
    __syncthreads();
    // bitonic sort 2048 (1024 threads = 1 pair each)
    for (unsigned k = 2; k <= GCAP; k <<= 1) {
        for (unsigned j = k >> 1; j; j >>= 1) {
            unsigned p = tid;
            unsigned i = ((p & ~(j - 1)) << 1) | (p & (j - 1));
            unsigned ixj = i | j;
            uint64_t x = s[i], y = s[ixj];
            bool up = ((i & k) == 0);
            if (up ? (x > y) : (x < y)) { s[i] = y; s[ixj] = x; }
            __syncthreads();
        }
    }
    // decode ranks [base, base+cnt) ∩ [0, PRE_NMS)
    float him = im_info[b * 3 + 0], wim = im_info[b * 3 + 1];
    float ymax = __fsub_rn(him, 1.0f), xmax = __fsub_rn(wim, 1.0f);
    for (int r = tid; r < GCAP; r += 1024) {
        uint32_t P = base + (uint32_t)r;
        uint32_t idx = (uint32_t)s[r];
        if (r < (int)cnt && P < PRE_NMS && idx < NPER) {
            int a = idx % A_NUM;
            int p = idx / A_NUM;
            int wc = p % W_FEAT, hr = p / W_FEAT;
            float ax1 = ANC[a][0] + (float)(wc * 16);
            float ay1 = ANC[a][1] + (float)(hr * 16);
            float ax2 = ANC[a][2] + (float)(wc * 16);
            float ay2 = ANC[a][3] + (float)(hr * 16);
            const float* dp = deltas + (size_t)(b * 36 + a * 4) * HWSZ + p;
            float dx = dp[0], dy = dp[HWSZ], dw = dp[2 * HWSZ], dh = dp[3 * HWSZ];
            float ww = __fadd_rn(__fsub_rn(ax2, ax1), 1.0f);
            float hh = __fadd_rn(__fsub_rn(ay2, ay1), 1.0f);
            float cx = __fadd_rn(ax1, __fmul_rn(0.5f, ww));
            float cy = __fadd_rn(ay1, __fmul_rn(0.5f, hh));
            float pcx = __fadd_rn(__fmul_rn(dx, ww), cx);
            float pcy = __fadd_rn(__fmul_rn(dy, hh), cy);
            float ew = (float)exp((double)dw);
            float eh = (float)exp((double)dh);
            float pw = __fmul_rn(ew, ww);
            float ph = __fmul_rn(eh, hh);
            float x1 = __fsub_rn(pcx, __fmul_rn(0.5f, pw));
            float y1 = __fsub_rn(pcy, __fmul_rn(0.5f, ph));
            float x2 = __fadd_rn(pcx, __fmul_rn(0.5f, pw));
            float y2 = __fadd_rn(pcy, __fmul_rn(0.5f, ph));
            float4 bx;
            bx.x = fminf(fmaxf(x1, 0.0f), xmax);
            bx.y = fminf(fmaxf(y1, 0.0f), ymax);
            bx.z = fminf(fmaxf(x2, 0.0f), xmax);
            bx.w = fminf(fmaxf(y2, 0.0f), ymax);
            boxes[(size_t)b * PRE_NMS + P] = bx;
        }
    }
}

// ---- K5: suppression bitmask, TRANSPOSED layout masks[cand][word] -----------
// masks[(b*NC + i)*NW + tj] = bits jj where j=tj*64+jj > i and IoU(i,j) > 0.7
__global__ __launch_bounds__(256) void k_mask(const float4* __restrict__ boxes,
                                              uint64_t* __restrict__ masks,
                                              int NC, int NW, int T) {
    int b = blockIdx.y;
    int wv = threadIdx.x >> 6, lane = threadIdx.x & 63;
    int t = blockIdx.x * 4 + wv;
    if (t >= T) return;
    int ti = 0, rem = t;
    while (rem >= NW - ti) { rem -= NW - ti; ++ti; }   // upper-triangle map
    int tj = ti + rem;
    __shared__ float4 colb[4][64];
    __shared__ float  cola[4][64];
    const float4* bb = boxes + (size_t)b * PRE_NMS;
    int i = ti * 64 + lane;
    float4 c = bb[i];
    float ca = area_of(c);
    float4 q0 = bb[tj * 64 + lane];
    colb[wv][lane] = q0;
    cola[wv][lane] = area_of(q0);
    asm volatile("s_waitcnt lgkmcnt(0)" ::: "memory");  // single-wave LDS sync
    __builtin_amdgcn_wave_barrier();
    uint64_t m = 0;
    if (ti == tj) {
#pragma unroll
        for (int jj = 0; jj < 64; ++jj) {
            bool hit = (jj > lane) && iou_gt(colb[wv][jj], cola[wv][jj], c, ca);
            m |= ((uint64_t)(hit ? 1u : 0u)) << jj;
        }
    } else {
#pragma unroll
        for (int jj = 0; jj < 64; ++jj) {
            bool hit = iou_gt(colb[wv][jj], cola[wv][jj], c, ca);
            m |= ((uint64_t)(hit ? 1u : 0u)) << jj;
        }
    }
    masks[((size_t)b * NC + i) * NW + tj] = m;   // transposed: [cand][word]
}

// kept-list register helpers (slot s holds kept[s*64+lane])
#define PROC(P)                                                                \
    do {                                                                       \
        float ca = area_of(P);                                                 \
        bool viol = false;                                                     \
        if (K > 0)   viol |= (lane       < K) & iou_gt(k0, a0, P, ca);         \
        if (K > 64)  viol |= (lane + 64  < K) & iou_gt(k1, a1, P, ca);         \
        if (K > 128) viol |= (lane + 128 < K) & iou_gt(k2, a2, P, ca);         \
        if (K > 192) viol |= (lane + 192 < K) & iou_gt(k3, a3, P, ca);         \
        if (K > 256) viol |= (lane + 256 < K) & iou_gt(k4, a4, P, ca);         \
        if (!__any((int)viol)) {                                               \
            int sl = K >> 6, tg = K & 63;                                      \
            if (lane == tg) {                                                  \
                switch (sl) {                                                  \
                case 0: k0 = P; a0 = ca; break;                                \
                case 1: k1 = P; a1 = ca; break;                                \
                case 2: k2 = P; a2 = ca; break;                                \
                case 3: k3 = P; a3 = ca; break;                                \
                default: k4 = P; a4 = ca; break;                               \
                }                                                              \
            }                                                                  \
            ++K;                                                               \
        }                                                                      \
    } while (0)

// one word-body slot: compile-time bit S_BIT in SW (scalar imm test), ring RG.
// Common path: imm bit-test + ring reload. Kept path (rare): slot update,
// sup |= RG&lm, refresh swL/swH via readlane, K++/fin.
#define RSLOT(SW, S_BIT, RG)                                                   \
    do {                                                                       \
        if (!fin) {                                                            \
            if (!((SW >> (S_BIT)) & 1u)) {                                     \
                int sl = K >> 6, tg = K & 63;                                  \
                if (lane == tg) {                                              \
                    switch (sl) {                                              \
                    case 0: i0 = i; break;                                     \
                    case 1: i1 = i; break;                                     \
                    case 2: i2 = i; break;                                     \
                    case 3: i3 = i; break;                                     \
                    default: i4 = i; break;                                    \
                    }                                                          \
                }                                                              \
                sup |= RG & lm;                                                \
                swL = (unsigned)__builtin_amdgcn_readlane((int)(unsigned)sup, w);          \
                swH = (unsigned)__builtin_amdgcn_readlane((int)(unsigned)(sup >> 32), w);  \
                ++K;                                                           \
                if (K >= POST_NMS) fin = true;                                 \
            }                                                                  \
            int nx = i + 32; if (nx >= NC) nx = NC - 1;                        \
            RG = mrow[(size_t)nx * NW];                                        \
            ++i;                                                               \
        }                                                                      \
    } while (0)

// ---- K6: greedy resolve — word-body walk, compile-time bit tests, ring-32 ---
__global__ __launch_bounds__(64) void k_resolve(const float4* __restrict__ boxes,
                                                const uint64_t* __restrict__ masks,
                                                int NC, int NW,
                                                float* __restrict__ out) {
    int b = blockIdx.x, lane = threadIdx.x;
    const float4* bb = boxes + (size_t)b * PRE_NMS;
    int K = 0;
    int i0 = 0, i1 = 0, i2 = 0, i3 = 0, i4 = 0;
    bool fin = false;

    if (NC > 0) {
        const uint64_t* mrow =
            masks + (size_t)b * NC * NW + (lane < NW ? lane : NW - 1);
        uint64_t sup = 0;
        uint64_t lm = (lane < NW) ? ~0ull : 0ull;    // sup-update lane mask
        // ring: slot s (global cand i) uses q[i&31]; 64 | 32 so static per slot
        uint64_t q0  = mrow[0*NW],  q1  = mrow[1*NW],  q2  = mrow[2*NW],  q3  = mrow[3*NW];
        uint64_t q4  = mrow[4*NW],  q5  = mrow[5*NW],  q6  = mrow[6*NW],  q7  = mrow[7*NW];
        uint64_t q8  = mrow[8*NW],  q9  = mrow[9*NW],  q10 = mrow[10*NW], q11 = mrow[11*NW];
        uint64_t q12 = mrow[12*NW], q13 = mrow[13*NW], q14 = mrow[14*NW], q15 = mrow[15*NW];
        uint64_t q16 = mrow[16*NW], q17 = mrow[17*NW], q18 = mrow[18*NW], q19 = mrow[19*NW];
        uint64_t q20 = mrow[20*NW], q21 = mrow[21*NW], q22 = mrow[22*NW], q23 = mrow[23*NW];
        uint64_t q24 = mrow[24*NW], q25 = mrow[25*NW], q26 = mrow[26*NW], q27 = mrow[27*NW];
        uint64_t q28 = mrow[28*NW], q29 = mrow[29*NW], q30 = mrow[30*NW], q31 = mrow[31*NW];
        int i = 0;
        for (int w = 0; w < NW && !fin; ++w) {
            unsigned swL = (unsigned)__builtin_amdgcn_readlane((int)(unsigned)sup, w);
            unsigned swH = (unsigned)__builtin_amdgcn_readlane((int)(unsigned)(sup >> 32), w);
            RSLOT(swL, 0, q0);  RSLOT(swL, 1, q1);  RSLOT(swL, 2, q2);  RSLOT(swL, 3, q3);
            RSLOT(swL, 4, q4);  RSLOT(swL, 5, q5);  RSLOT(swL, 6, q6);  RSLOT(swL, 7, q7);
            RSLOT(swL, 8, q8);  RSLOT(swL, 9, q9);  RSLOT(swL,10, q10); RSLOT(swL,11, q11);
            RSLOT(swL,12, q12); RSLOT(swL,13, q13); RSLOT(swL,14, q14); RSLOT(swL,15, q15);
            RSLOT(swL,16, q16); RSLOT(swL,17, q17); RSLOT(swL,18, q18); RSLOT(swL,19, q19);
            RSLOT(swL,20, q20); RSLOT(swL,21, q21); RSLOT(swL,22, q22); RSLOT(swL,23, q23);
            RSLOT(swL,24, q24); RSLOT(swL,25, q25); RSLOT(swL,26, q26); RSLOT(swL,27, q27);
            RSLOT(swL,28, q28); RSLOT(swL,29, q29); RSLOT(swL,30, q30); RSLOT(swL,31, q31);
            RSLOT(swH, 0, q0);  RSLOT(swH, 1, q1);  RSLOT(swH, 2, q2);  RSLOT(swH, 3, q3);
            RSLOT(swH, 4, q4);  RSLOT(swH, 5, q5);  RSLOT(swH, 6, q6);  RSLOT(swH, 7, q7);
            RSLOT(swH, 8, q8);  RSLOT(swH, 9, q9);  RSLOT(swH,10, q10); RSLOT(swH,11, q11);
            RSLOT(swH,12, q12); RSLOT(swH,13, q13); RSLOT(swH,14, q14); RSLOT(swH,15, q15);
            RSLOT(swH,16, q16); RSLOT(swH,17, q17); RSLOT(swH,18, q18); RSLOT(swH,19, q19);
            RSLOT(swH,20, q20); RSLOT(swH,21, q21); RSLOT(swH,22, q22); RSLOT(swH,23, q23);
            RSLOT(swH,24, q24); RSLOT(swH,25, q25); RSLOT(swH,26, q26); RSLOT(swH,27, q27);
            RSLOT(swH,28, q28); RSLOT(swH,29, q29); RSLOT(swH,30, q30); RSLOT(swH,31, q31);
        }
    }

    // gather kept boxes into lane-cycled registers
    float4 k0, k1, k2, k3, k4;
    float a0, a1, a2, a3, a4;
    { int id = (lane       < K) ? i0 : 0; k0 = bb[id]; a0 = area_of(k0); }
    { int id = (lane + 64  < K) ? i1 : 0; k1 = bb[id]; a1 = area_of(k1); }
    { int id = (lane + 128 < K) ? i2 : 0; k2 = bb[id]; a2 = area_of(k2); }
    { int id = (lane + 192 < K) ? i3 : 0; k3 = bb[id]; a3 = area_of(k3); }
    { int id = (lane + 256 < K) ? i4 : 0; k4 = bb[id]; a4 = area_of(k4); }

    // fallback: continue exact greedy walk past NC if needed
    if (!fin && NC < PRE_NMS) {
        float4 p0 = bb[NC + 0], p1 = bb[NC + 1], p2 = bb[NC + 2], p3 = bb[NC + 3];
        bool done = false;
        for (int r = NC; r < PRE_NMS && !done; r += 4) {
            int n = r + 4;
            float4 n0 = bb[(n + 0 < PRE_NMS) ? n + 0 : PRE_NMS - 1];
            float4 n1 = bb[(n + 1 < PRE_NMS) ? n + 1 : PRE_NMS - 1];
            float4 n2 = bb[(n + 2 < PRE_NMS) ? n + 2 : PRE_NMS - 1];
            float4 n3 = bb[(n + 3 < PRE_NMS) ? n + 3 : PRE_NMS - 1];
            PROC(p0); if (K >= POST_NMS) done = true;
            if (!done) { PROC(p1); if (K >= POST_NMS) done = true; }
            if (!done) { PROC(p2); if (K >= POST_NMS) done = true; }
            if (!done) { PROC(p3); if (K >= POST_NMS) done = true; }
            p0 = n0; p1 = n1; p2 = n2; p3 = n3;
        }
    }

    // output kept[s*64+lane]
#pragma unroll
    for (int s = 0; s < 5; ++s) {
        int idx = s * 64 + lane;
        if (idx < POST_NMS) {
            float4 c;
            switch (s) {
            case 0: c = k0; break;
            case 1: c = k1; break;
            case 2: c = k2; break;
            case 3: c = k3; break;
            default: c = k4; break;
            }
            bool v = idx < K;
            float* o = out + (size_t)(b * POST_NMS + idx) * 5;
            o[0] = (float)b;
            o[1] = v ? c.x : 0.f;
            o[2] = v ? c.y : 0.f;
            o[3] = v ? c.z : 0.f;
            o[4] = v ? c.w : 0.f;
        }
    }
}

extern "C" void kernel_launch(void* const* d_in, const int* in_sizes, int n_in,
                              void* d_out, int out_size, void* d_ws, size_t ws_size,
                              hipStream_t stream) {
    const float* scores  = (const float*)d_in[0];
    const float* deltas  = (const float*)d_in[1];
    const float* im_info = (const float*)d_in[2];
    float* out = (float*)d_out;
    char* ws = (char*)d_ws;

    // layout: boxes | scum | gbase+gcnt(8KB) | subhist(S MB) | cand | masks
    const size_t boxB   = (size_t)B_NUM * PRE_NMS * 16;       // 1,536,000
    const size_t scumB  = (size_t)B_NUM * NBINS * 4;          // 1,048,576
    const size_t metaB  = 8192;                               // gbase 512B + gcnt 6KB
    const size_t candB  = (size_t)B_NUM * NGRP * GCAP * 8;    // 1,572,864
    const size_t fixedB = boxB + scumB + metaB;
    int NC = 0, S = 1;
    const int lad[2] = {2048, 1024};
    for (int li = 0; li < 2 && !NC; ++li) {
        size_t mb = 2ull * lad[li] * lad[li];                 // 16*NC*NW*8 = 2*NC^2
        if (fixedB + 1048576ull + candB + mb <= ws_size) {
            NC = lad[li];
            for (int ss = 8; ss >= 1; ss >>= 1)
                if (fixedB + (size_t)ss * 1048576ull + candB + mb <= ws_size) { S = ss; break; }
        }
    }
    if (!NC) { NC = 1024; S = 1; }
    int NW = NC / 64;

    float4*   boxes   = (float4*)ws;
    uint32_t* scum    = (uint32_t*)(ws + boxB);
    uint32_t* gbase   = (uint32_t*)(ws + boxB + scumB);
    uint32_t* gcnt    = (uint32_t*)(ws + boxB + scumB + 1024);
    uint32_t* subhist = (uint32_t*)(ws + fixedB);
    uint64_t* cand    = (uint64_t*)(ws + fixedB + (size_t)S * 1048576ull);
    uint64_t* masks   = (uint64_t*)(ws + fixedB + (size_t)S * 1048576ull + candB);

    dim3 gh(S, B_NUM);
    k_hist<<<gh, 1024, 0, stream>>>(scores, subhist);
    k_scan<<<B_NUM, 1024, 0, stream>>>(subhist, S, scum, gbase, gcnt);
    k_compact<<<gh, 1024, 0, stream>>>(scores, scum, cand, gcnt);
    dim3 gg(NGRP, B_NUM);
    k_group<<<gg, 1024, 0, stream>>>(cand, gcnt, deltas, im_info, gbase, boxes);
    int T = NW * (NW + 1) / 2;
    dim3 gm((T + 3) / 4, B_NUM);
    k_mask<<<gm, 256, 0, stream>>>(boxes, masks, NC, NW, T);
    k_resolve<<<B_NUM, 64, 0, stream>>>(boxes, masks, NC, NW, out);
}

// Round 18
// 142.263 us; speedup vs baseline: 1.2033x; 1.2033x over previous
//
#include <hip/hip_runtime.h>
#include <cstdint>
#include <cmath>

#define HWSZ    15000      // H*W = 100*150
#define W_FEAT  150
#define A_NUM   9
#define NPER    135000     // A_NUM * HWSZ
#define B_NUM   16
#define PRE_NMS 6000
#define POST_NMS 300
#define NBINS   16384      // top-14-bit histogram
#define GCAP    2048       // per-group sort capacity
#define NGRP    6          // ceil(6000/1024)

// 9 base anchors from generate_anchors(16,[0.5,1,2],[8,16,32]).
__device__ __constant__ float ANC[9][4] = {
    {-84.f,  -40.f,  99.f,  55.f},
    {-176.f, -88.f, 191.f, 103.f},
    {-360.f,-184.f, 375.f, 199.f},
    {-56.f,  -56.f,  71.f,  71.f},
    {-120.f,-120.f, 135.f, 135.f},
    {-248.f,-248.f, 263.f, 263.f},
    {-36.f,  -80.f,  51.f,  95.f},
    {-80.f, -168.f,  95.f, 183.f},
    {-168.f,-344.f, 183.f, 359.f}};

__device__ __forceinline__ uint32_t fkey(float s) {
    uint32_t u = __float_as_uint(s);
    return (u & 0x80000000u) ? ~u : (u | 0x80000000u);  // monotone key
}

// EXACT replacement for  __fdiv_rn(inter,den) > 0.7f  (see r6 derivation):
// m = midpoint(0.7f,next(0.7f)) = 0x1.666667p-1 (25 bits); m*(double)den exact.
__device__ __forceinline__ bool iou_gt(const float4& q, float qa,
                                       const float4& c, float ca) {
    float xx1 = fmaxf(q.x, c.x);
    float yy1 = fmaxf(q.y, c.y);
    float xx2 = fminf(q.z, c.z);
    float yy2 = fminf(q.w, c.w);
    float iw = fmaxf(0.0f, __fadd_rn(__fsub_rn(xx2, xx1), 1.0f));
    float ih = fmaxf(0.0f, __fadd_rn(__fsub_rn(yy2, yy1), 1.0f));
    float inter = __fmul_rn(iw, ih);
    float den = __fsub_rn(__fadd_rn(qa, ca), inter);
    return (double)inter >= 0x1.666667p-1 * (double)den;
}

__device__ __forceinline__ float area_of(const float4& c) {
    return __fmul_rn(__fadd_rn(__fsub_rn(c.z, c.x), 1.0f),
                     __fadd_rn(__fsub_rn(c.w, c.y), 1.0f));
}

// ---- K1: per-slice LDS histograms, atomically merged into ONE global hist ---
__global__ __launch_bounds__(1024) void k_hist(const float* __restrict__ scores,
                                               uint32_t* __restrict__ ghist) {
    __shared__ uint32_t hist[NBINS];          // 64KB
    int b = blockIdx.y, sx = blockIdx.x, S = gridDim.x, tid = threadIdx.x;
    for (int i = tid; i < NBINS; i += 1024) hist[i] = 0;
    __syncthreads();
    const float4* sc4 = (const float4*)(scores + (size_t)(b * 18 + 9) * HWSZ);
    int nf4 = NPER / 4;                       // 33750
    int per = (nf4 + S - 1) / S;
    int lo = sx * per, hi = min(lo + per, nf4);
    for (int i = lo + tid; i < hi; i += 1024) {
        float4 v = sc4[i];
        atomicAdd(&hist[fkey(v.x) >> 18], 1u);
        atomicAdd(&hist[fkey(v.y) >> 18], 1u);
        atomicAdd(&hist[fkey(v.z) >> 18], 1u);
        atomicAdd(&hist[fkey(v.w) >> 18], 1u);
    }
    __syncthreads();
    uint32_t* out = ghist + (size_t)b * NBINS;
    for (int i = tid; i < NBINS; i += 1024) {
        uint32_t v = hist[i];
        if (v) atomicAdd(&out[i], v);         // sparse coalesced merge
    }
}

// ---- K2: per-bin exclusive-from-top cum table + group bases + gcnt zero -----
__global__ __launch_bounds__(1024) void k_scan(const uint32_t* __restrict__ ghist,
                                               uint32_t* __restrict__ scum,
                                               uint32_t* __restrict__ gbase,
                                               uint32_t* __restrict__ gcnt) {
    __shared__ uint32_t tl[NBINS];            // 64KB hist
    __shared__ uint32_t psum[1024];
    __shared__ uint32_t gb[8];
    int b = blockIdx.x, tid = threadIdx.x;
    for (int i = tid; i < NBINS; i += 1024)
        tl[i] = ghist[(size_t)b * NBINS + i];
    if (tid < 8) gb[tid] = 0xFFFFFFFFu;
    if (tid < NGRP) gcnt[(b * NGRP + tid) * 16] = 0;   // replaces memset dispatch
    __syncthreads();
    int base = NBINS - 16 * (tid + 1);        // chunk tid: descending bins
    uint32_t csum = 0;
#pragma unroll
    for (int i = 0; i < 16; ++i) csum += tl[base + i];
    psum[tid] = csum;
    __syncthreads();
    for (int off = 1; off < 1024; off <<= 1) {
        uint32_t v = (tid >= off) ? psum[tid - off] : 0u;
        __syncthreads();
        psum[tid] += v;
        __syncthreads();
    }
    uint32_t c = tid ? psum[tid - 1] : 0u;    // exclusive cum before this chunk
    for (int i = 15; i >= 0; --i) {           // bins descending within chunk
        uint32_t t = tl[base + i];
        scum[(size_t)b * NBINS + base + i] = c;
        if (t && c < PRE_NMS) atomicMin(&gb[c >> 10], c);
        c += t;
    }
    __syncthreads();
    if (tid < 8) gbase[b * 8 + tid] = gb[tid];
}

// ---- K3: single-pass compact -> per-group global candidate buffers ----------
__global__ __launch_bounds__(1024) void k_compact(
        const float* __restrict__ scores, const uint32_t* __restrict__ scum,
        uint64_t* __restrict__ cand, uint32_t* __restrict__ gcnt) {
    __shared__ uint32_t sl[NBINS];            // 64KB scum cache
    __shared__ uint32_t lc[NGRP], lb[NGRP];
    int b = blockIdx.y, sx = blockIdx.x, S = gridDim.x, tid = threadIdx.x;
    for (int i = tid; i < NBINS; i += 1024) sl[i] = scum[(size_t)b * NBINS + i];
    if (tid < NGRP) lc[tid] = 0;
    __syncthreads();
    const float4* sc4 = (const float4*)(scores + (size_t)(b * 18 + 9) * HWSZ);
    int nf4 = NPER / 4;
    int per = (nf4 + S - 1) / S;
    int lo = sx * per, hi = min(lo + per, nf4);
    for (int i0 = lo; i0 < hi; i0 += 1024) {
        int i = i0 + tid;
        bool w[4];
        uint32_t gg[4], pp[4];
        uint64_t rec[4];
#pragma unroll
        for (int c = 0; c < 4; ++c) w[c] = false;
        if (i < hi) {
            float4 v = sc4[i];
            float cc[4] = {v.x, v.y, v.z, v.w};
#pragma unroll
            for (int c = 0; c < 4; ++c) {
                uint32_t k = fkey(cc[c]);
                uint32_t sc = sl[k >> 18];
                if (sc < PRE_NMS) {           // in top-6000 by bin
                    w[c] = true;
                    gg[c] = sc >> 10;         // rank group 0..5
                    pp[c] = atomicAdd(&lc[gg[c]], 1u);
                    int e = 4 * i + c;        // e = a*HWSZ + p
                    int a = e / HWSZ, p = e - a * HWSZ;
                    rec[c] = ((uint64_t)(~k) << 32) | (uint32_t)(p * A_NUM + a);
                }
            }
        }
        __syncthreads();
        if (tid < NGRP && lc[tid])            // one global atomic per group/chunk
            lb[tid] = atomicAdd(&gcnt[(b * NGRP + tid) * 16], lc[tid]);
        __syncthreads();
#pragma unroll
        for (int c = 0; c < 4; ++c)
            if (w[c]) {
                uint32_t pos = lb[gg[c]] + pp[c];
                if (pos < GCAP)
                    cand[((size_t)b * NGRP + gg[c]) * GCAP + pos] = rec[c];
            }
        __syncthreads();
        if (tid < NGRP) lc[tid] = 0;
        __syncthreads();
    }
}

// ---- K4: per-group bitonic(2048) + decode (no score re-read) ----------------
__global__ __launch_bounds__(1024) void k_group(
        const uint64_t* __restrict__ cand, const uint32_t* __restrict__ gcnt,
        const float* __restrict__ deltas, const float* __restrict__ im_info,
        const uint32_t* __restrict__ gbase, float4* __restrict__ boxes) {
    __shared__ uint64_t s[GCAP];              // 16KB sort buffer
    int b = blockIdx.y, g = blockIdx.x, tid = threadIdx.x;
    uint32_t base = gbase[b * 8 + g];
    if (base == 0xFFFFFFFFu) return;          // empty group
    uint32_t cnt = min(gcnt[(b * NGRP + g) * 16], (uint32_t)GCAP);
    for (int i = tid; i < GCAP; i += 1024)
        s[i] = (i < (int)cnt) ? cand[((size_t)b * NGRP + g) * GCAP + i] : ~0ull;
    __syncthreads();
    // bitonic sort 2048 (1024 threads = 1 pair each)
    for (unsigned k = 2; k <= GCAP; k <<= 1) {
        for (unsigned j = k >> 1; j; j >>= 1) {
            unsigned p = tid;
            unsigned i = ((p & ~(j - 1)) << 1) | (p & (j - 1));
            unsigned ixj = i | j;
            uint64_t x = s[i], y = s[ixj];
            bool up = ((i & k) == 0);
            if (up ? (x > y) : (x < y)) { s[i] = y; s[ixj] = x; }
            __syncthreads();
        }
    }
    // decode ranks [base, base+cnt) ∩ [0, PRE_NMS)
    float him = im_info[b * 3 + 0], wim = im_info[b * 3 + 1];
    float ymax = __fsub_rn(him, 1.0f), xmax = __fsub_rn(wim, 1.0f);
    for (int r = tid; r < GCAP; r += 1024) {
        uint32_t P = base + (uint32_t)r;
        uint32_t idx = (uint32_t)s[r];
        if (r < (int)cnt && P < PRE_NMS && idx < NPER) {
            int a = idx % A_NUM;
            int p = idx / A_NUM;
            int wc = p % W_FEAT, hr = p / W_FEAT;
            float ax1 = ANC[a][0] + (float)(wc * 16);
            float ay1 = ANC[a][1] + (float)(hr * 16);
            float ax2 = ANC[a][2] + (float)(wc * 16);
            float ay2 = ANC[a][3] + (float)(hr * 16);
            const float* dp = deltas + (size_t)(b * 36 + a * 4) * HWSZ + p;
            float dx = dp[0], dy = dp[HWSZ], dw = dp[2 * HWSZ], dh = dp[3 * HWSZ];
            float ww = __fadd_rn(__fsub_rn(ax2, ax1), 1.0f);
            float hh = __fadd_rn(__fsub_rn(ay2, ay1), 1.0f);
            float cx = __fadd_rn(ax1, __fmul_rn(0.5f, ww));
            float cy = __fadd_rn(ay1, __fmul_rn(0.5f, hh));
            float pcx = __fadd_rn(__fmul_rn(dx, ww), cx);
            float pcy = __fadd_rn(__fmul_rn(dy, hh), cy);
            float ew = (float)exp((double)dw);
            float eh = (float)exp((double)dh);
            float pw = __fmul_rn(ew, ww);
            float ph = __fmul_rn(eh, hh);
            float x1 = __fsub_rn(pcx, __fmul_rn(0.5f, pw));
            float y1 = __fsub_rn(pcy, __fmul_rn(0.5f, ph));
            float x2 = __fadd_rn(pcx, __fmul_rn(0.5f, pw));
            float y2 = __fadd_rn(pcy, __fmul_rn(0.5f, ph));
            float4 bx;
            bx.x = fminf(fmaxf(x1, 0.0f), xmax);
            bx.y = fminf(fmaxf(y1, 0.0f), ymax);
            bx.z = fminf(fmaxf(x2, 0.0f), xmax);
            bx.w = fminf(fmaxf(y2, 0.0f), ymax);
            boxes[(size_t)b * PRE_NMS + P] = bx;
        }
    }
}

// ---- K5: suppression bitmask, layout masks[word][cand] (r14, best) ----------
__global__ __launch_bounds__(256) void k_mask(const float4* __restrict__ boxes,
                                              uint64_t* __restrict__ masks,
                                              int NC, int NW, int T) {
    int b = blockIdx.y;
    int wv = threadIdx.x >> 6, lane = threadIdx.x & 63;
    int t = blockIdx.x * 4 + wv;
    if (t >= T) return;
    int ti = 0, rem = t;
    while (rem >= NW - ti) { rem -= NW - ti; ++ti; }   // upper-triangle map
    int tj = ti + rem;
    __shared__ float4 colb[4][64];
    __shared__ float  cola[4][64];
    const float4* bb = boxes + (size_t)b * PRE_NMS;
    int i = ti * 64 + lane;
    float4 c = bb[i];
    float ca = area_of(c);
    float4 q0 = bb[tj * 64 + lane];
    colb[wv][lane] = q0;
    cola[wv][lane] = area_of(q0);
    asm volatile("s_waitcnt lgkmcnt(0)" ::: "memory");  // single-wave LDS sync
    __builtin_amdgcn_wave_barrier();
    uint64_t m = 0;
    if (ti == tj) {
#pragma unroll
        for (int jj = 0; jj < 64; ++jj) {
            bool hit = (jj > lane) && iou_gt(colb[wv][jj], cola[wv][jj], c, ca);
            m |= ((uint64_t)(hit ? 1u : 0u)) << jj;
        }
    } else {
#pragma unroll
        for (int jj = 0; jj < 64; ++jj) {
            bool hit = iou_gt(colb[wv][jj], cola[wv][jj], c, ca);
            m |= ((uint64_t)(hit ? 1u : 0u)) << jj;
        }
    }
    masks[((size_t)b * NW + tj) * NC + i] = m;
}

// kept-list register helpers (slot s holds kept[s*64+lane])
#define PROC(P)                                                                \
    do {                                                                       \
        float ca = area_of(P);                                                 \
        bool viol = false;                                                     \
        if (K > 0)   viol |= (lane       < K) & iou_gt(k0, a0, P, ca);         \
        if (K > 64)  viol |= (lane + 64  < K) & iou_gt(k1, a1, P, ca);         \
        if (K > 128) viol |= (lane + 128 < K) & iou_gt(k2, a2, P, ca);         \
        if (K > 192) viol |= (lane + 192 < K) & iou_gt(k3, a3, P, ca);         \
        if (K > 256) viol |= (lane + 256 < K) & iou_gt(k4, a4, P, ca);         \
        if (!__any((int)viol)) {                                               \
            int sl = K >> 6, tg = K & 63;                                      \
            if (lane == tg) {                                                  \
                switch (sl) {                                                  \
                case 0: k0 = P; a0 = ca; break;                                \
                case 1: k1 = P; a1 = ca; break;                                \
                case 2: k2 = P; a2 = ca; break;                                \
                case 3: k3 = P; a3 = ca; break;                                \
                default: k4 = P; a4 = ca; break;                               \
                }                                                              \
            }                                                                  \
            ++K;                                                               \
        }                                                                      \
    } while (0)

// one mask-walk step: scalar readlane bit-test (no ballot); ring reload i+8
#define RSTEP(RG)                                                              \
    do {                                                                       \
        if (!fin && i < NC) {                                                  \
            unsigned half = (i & 32) ? (unsigned)(sup >> 32) : (unsigned)sup;  \
            unsigned sw = (unsigned)__builtin_amdgcn_readlane((int)half, i >> 6);\
            if (!((sw >> (i & 31)) & 1u)) {                                    \
                int sl = K >> 6, tg = K & 63;                                  \
                if (lane == tg) {                                              \
                    switch (sl) {                                              \
                    case 0: i0 = i; break;                                     \
                    case 1: i1 = i; break;                                     \
                    case 2: i2 = i; break;                                     \
                    case 3: i3 = i; break;                                     \
                    default: i4 = i; break;                                    \
                    }                                                          \
                }                                                              \
                if (lane < NW) sup |= RG;                                      \
                ++K;                                                           \
                if (K >= POST_NMS) fin = true;                                 \
            }                                                                  \
            int nx = i + 8; if (nx >= NC) nx = NC - 1;                         \
            RG = mrow[nx];                                                     \
            ++i;                                                               \
        }                                                                      \
    } while (0)

// ---- K6: greedy resolve — r14 structure (proven best: ring-8 + readlane) ----
__global__ __launch_bounds__(64) void k_resolve(const float4* __restrict__ boxes,
                                                const uint64_t* __restrict__ masks,
                                                int NC, int NW,
                                                float* __restrict__ out) {
    int b = blockIdx.x, lane = threadIdx.x;
    const float4* bb = boxes + (size_t)b * PRE_NMS;
    int K = 0;
    int i0 = 0, i1 = 0, i2 = 0, i3 = 0, i4 = 0;
    bool fin = false;

    if (NC > 0) {
        const uint64_t* mrow =
            masks + ((size_t)b * NW + (lane < NW ? lane : NW - 1)) * NC;
        uint64_t sup = 0;
        uint64_t r0 = mrow[0], r1 = mrow[1], r2 = mrow[2], r3 = mrow[3];
        uint64_t r4 = mrow[4], r5 = mrow[5], r6 = mrow[6], r7 = mrow[7];
        int i = 0;
        while (i < NC && !fin) {
            RSTEP(r0); RSTEP(r1); RSTEP(r2); RSTEP(r3);
            RSTEP(r4); RSTEP(r5); RSTEP(r6); RSTEP(r7);
        }
    }

    // gather kept boxes into lane-cycled registers
    float4 k0, k1, k2, k3, k4;
    float a0, a1, a2, a3, a4;
    { int id = (lane       < K) ? i0 : 0; k0 = bb[id]; a0 = area_of(k0); }
    { int id = (lane + 64  < K) ? i1 : 0; k1 = bb[id]; a1 = area_of(k1); }
    { int id = (lane + 128 < K) ? i2 : 0; k2 = bb[id]; a2 = area_of(k2); }
    { int id = (lane + 192 < K) ? i3 : 0; k3 = bb[id]; a3 = area_of(k3); }
    { int id = (lane + 256 < K) ? i4 : 0; k4 = bb[id]; a4 = area_of(k4); }

    // fallback: continue exact greedy walk past NC if needed
    if (!fin && NC < PRE_NMS) {
        float4 p0 = bb[NC + 0], p1 = bb[NC + 1], p2 = bb[NC + 2], p3 = bb[NC + 3];
        bool done = false;
        for (int r = NC; r < PRE_NMS && !done; r += 4) {
            int n = r + 4;
            float4 n0 = bb[(n + 0 < PRE_NMS) ? n + 0 : PRE_NMS - 1];
            float4 n1 = bb[(n + 1 < PRE_NMS) ? n + 1 : PRE_NMS - 1];
            float4 n2 = bb[(n + 2 < PRE_NMS) ? n + 2 : PRE_NMS - 1];
            float4 n3 = bb[(n + 3 < PRE_NMS) ? n + 3 : PRE_NMS - 1];
            PROC(p0); if (K >= POST_NMS) done = true;
            if (!done) { PROC(p1); if (K >= POST_NMS) done = true; }
            if (!done) { PROC(p2); if (K >= POST_NMS) done = true; }
            if (!done) { PROC(p3); if (K >= POST_NMS) done = true; }
            p0 = n0; p1 = n1; p2 = n2; p3 = n3;
        }
    }

    // output kept[s*64+lane]
#pragma unroll
    for (int s = 0; s < 5; ++s) {
        int idx = s * 64 + lane;
        if (idx < POST_NMS) {
            float4 c;
            switch (s) {
            case 0: c = k0; break;
            case 1: c = k1; break;
            case 2: c = k2; break;
            case 3: c = k3; break;
            default: c = k4; break;
            }
            bool v = idx < K;
            float* o = out + (size_t)(b * POST_NMS + idx) * 5;
            o[0] = (float)b;
            o[1] = v ? c.x : 0.f;
            o[2] = v ? c.y : 0.f;
            o[3] = v ? c.z : 0.f;
            o[4] = v ? c.w : 0.f;
        }
    }
}

extern "C" void kernel_launch(void* const* d_in, const int* in_sizes, int n_in,
                              void* d_out, int out_size, void* d_ws, size_t ws_size,
                              hipStream_t stream) {
    const float* scores  = (const float*)d_in[0];
    const float* deltas  = (const float*)d_in[1];
    const float* im_info = (const float*)d_in[2];
    float* out = (float*)d_out;
    char* ws = (char*)d_ws;

    // layout: boxes | scum | gbase+gcnt(8KB) | ghist(1MB) | cand | masks
    const size_t boxB   = (size_t)B_NUM * PRE_NMS * 16;       // 1,536,000
    const size_t scumB  = (size_t)B_NUM * NBINS * 4;          // 1,048,576
    const size_t metaB  = 8192;                               // gbase 512B + gcnt 6KB
    const size_t histB  = (size_t)B_NUM * NBINS * 4;          // 1,048,576
    const size_t candB  = (size_t)B_NUM * NGRP * GCAP * 8;    // 1,572,864
    const size_t fixedB = boxB + scumB + metaB;
    int NC = 0;
    const int lad[2] = {2048, 1024};
    for (int li = 0; li < 2 && !NC; ++li) {
        size_t mb = 2ull * lad[li] * lad[li];                 // 16*NW*NC*8 = 2*NC^2
        if (fixedB + histB + candB + mb <= ws_size) NC = lad[li];
    }
    if (!NC) NC = 1024;
    int NW = NC / 64;
    int S = 8;                                // k_hist slice parallelism

    float4*   boxes = (float4*)ws;
    uint32_t* scum  = (uint32_t*)(ws + boxB);
    uint32_t* gbase = (uint32_t*)(ws + boxB + scumB);
    uint32_t* gcnt  = (uint32_t*)(ws + boxB + scumB + 1024);
    uint32_t* ghist = (uint32_t*)(ws + fixedB);
    uint64_t* cand  = (uint64_t*)(ws + fixedB + histB);
    uint64_t* masks = (uint64_t*)(ws + fixedB + histB + candB);

    hipMemsetAsync(ghist, 0, histB, stream);

    dim3 gh(S, B_NUM);
    k_hist<<<gh, 1024, 0, stream>>>(scores, ghist);
    k_scan<<<B_NUM, 1024, 0, stream>>>(ghist, scum, gbase, gcnt);
    k_compact<<<gh, 1024, 0, stream>>>(scores, scum, cand, gcnt);
    dim3 gg(NGRP, B_NUM);
    k_group<<<gg, 1024, 0, stream>>>(cand, gcnt, deltas, im_info, gbase, boxes);
    int T = NW * (NW + 1) / 2;
    dim3 gm((T + 3) / 4, B_NUM);
    k_mask<<<gm, 256, 0, stream>>>(boxes, masks, NC, NW, T);
    k_resolve<<<B_NUM, 64, 0, stream>>>(boxes, masks, NC, NW, out);
}